// Round 4
// baseline (317.375 us; speedup 1.0000x reference)
//
#include <hip/hip_runtime.h>
#include <math.h>

// Problem constants (fixed by the reference)
constexpr int B     = 8;
constexpr int N_PER = 2048;
constexpr int C     = 256;
constexpr int KG    = 16;
constexpr int KTOP  = 512;
constexpr int KNN   = 32;
constexpr int N     = B * N_PER;   // 16384
constexpr float EPS = 1e-5f;

// ---------------------------------------------------------------------------
// K1: T = x @ theta_w.T ;  R = x + x @ phi_w.T + (theta_b + phi_b) - T
// 128x64 tile, 8x4 dual accumulators, DOUBLE-BUFFERED LDS (1 barrier/tile).
// grid (N/128, C/64) = 512 blocks, block 256.
// ---------------------------------------------------------------------------
__global__ __launch_bounds__(256, 2) void k1_dual_gemm(
    const float* __restrict__ x, const float* __restrict__ thw,
    const float* __restrict__ phw, const float* __restrict__ thb,
    const float* __restrict__ phb, float* __restrict__ T, float* __restrict__ R)
{
    constexpr int BK = 16, STX = 132, STW = 68;
    __shared__ float Xs[2][BK * STX];
    __shared__ float Wt[2][BK * STW];
    __shared__ float Wp[2][BK * STW];
    const int tid  = threadIdx.x;
    const int row0 = blockIdx.x * 128;
    const int n0   = blockIdx.y * 64;
    const int tx = tid & 15, ty = tid >> 4;       // 8 rows x 4 cols per thread
    const int lm = tid >> 1, lq = (tid & 1) * 8;  // X stage: 128 rows x 16 k
    const int wm = tid >> 2, wq = (tid & 3) * 4;  // W stage: 64 rows x 16 k

    float aT[8][4] = {{0.f}}, aQ[8][4] = {{0.f}};

    // prologue: load tile 0, store into buffer 0
    float4 nx0 = *(const float4*)(x   + (size_t)(row0 + lm) * C + lq);
    float4 nx1 = *(const float4*)(x   + (size_t)(row0 + lm) * C + lq + 4);
    float4 nt  = *(const float4*)(thw + (size_t)(n0   + wm) * C + wq);
    float4 np_ = *(const float4*)(phw + (size_t)(n0   + wm) * C + wq);
    Xs[0][(lq + 0) * STX + lm] = nx0.x;  Xs[0][(lq + 1) * STX + lm] = nx0.y;
    Xs[0][(lq + 2) * STX + lm] = nx0.z;  Xs[0][(lq + 3) * STX + lm] = nx0.w;
    Xs[0][(lq + 4) * STX + lm] = nx1.x;  Xs[0][(lq + 5) * STX + lm] = nx1.y;
    Xs[0][(lq + 6) * STX + lm] = nx1.z;  Xs[0][(lq + 7) * STX + lm] = nx1.w;
    Wt[0][(wq + 0) * STW + wm] = nt.x;   Wt[0][(wq + 1) * STW + wm] = nt.y;
    Wt[0][(wq + 2) * STW + wm] = nt.z;   Wt[0][(wq + 3) * STW + wm] = nt.w;
    Wp[0][(wq + 0) * STW + wm] = np_.x;  Wp[0][(wq + 1) * STW + wm] = np_.y;
    Wp[0][(wq + 2) * STW + wm] = np_.z;  Wp[0][(wq + 3) * STW + wm] = np_.w;
    __syncthreads();

    int p = 0;
    for (int k0 = 0; k0 < C; k0 += BK) {
        const int kn = k0 + BK;
        if (kn < C) {   // prefetch next tile into registers
            nx0 = *(const float4*)(x   + (size_t)(row0 + lm) * C + kn + lq);
            nx1 = *(const float4*)(x   + (size_t)(row0 + lm) * C + kn + lq + 4);
            nt  = *(const float4*)(thw + (size_t)(n0   + wm) * C + kn + wq);
            np_ = *(const float4*)(phw + (size_t)(n0   + wm) * C + kn + wq);
        }
        const float* Xp = Xs[p];
        const float* Tp = Wt[p];
        const float* Pp = Wp[p];
#pragma unroll
        for (int k = 0; k < BK; ++k) {
            float4 alo = *(const float4*)&Xp[k * STX + ty * 8];
            float4 ahi = *(const float4*)&Xp[k * STX + ty * 8 + 4];
            float4 tv4 = *(const float4*)&Tp[k * STW + tx * 4];
            float4 pv4 = *(const float4*)&Pp[k * STW + tx * 4];
            float av[8] = {alo.x, alo.y, alo.z, alo.w, ahi.x, ahi.y, ahi.z, ahi.w};
            float tv[4] = {tv4.x, tv4.y, tv4.z, tv4.w};
            float pv[4] = {pv4.x, pv4.y, pv4.z, pv4.w};
#pragma unroll
            for (int i2 = 0; i2 < 8; ++i2)
#pragma unroll
                for (int j2 = 0; j2 < 4; ++j2) {
                    aT[i2][j2] += av[i2] * tv[j2];
                    aQ[i2][j2] += av[i2] * pv[j2];
                }
        }
        if (kn < C) {   // store prefetched tile into the other buffer
            const int q = p ^ 1;
            Xs[q][(lq + 0) * STX + lm] = nx0.x;  Xs[q][(lq + 1) * STX + lm] = nx0.y;
            Xs[q][(lq + 2) * STX + lm] = nx0.z;  Xs[q][(lq + 3) * STX + lm] = nx0.w;
            Xs[q][(lq + 4) * STX + lm] = nx1.x;  Xs[q][(lq + 5) * STX + lm] = nx1.y;
            Xs[q][(lq + 6) * STX + lm] = nx1.z;  Xs[q][(lq + 7) * STX + lm] = nx1.w;
            Wt[q][(wq + 0) * STW + wm] = nt.x;   Wt[q][(wq + 1) * STW + wm] = nt.y;
            Wt[q][(wq + 2) * STW + wm] = nt.z;   Wt[q][(wq + 3) * STW + wm] = nt.w;
            Wp[q][(wq + 0) * STW + wm] = np_.x;  Wp[q][(wq + 1) * STW + wm] = np_.y;
            Wp[q][(wq + 2) * STW + wm] = np_.z;  Wp[q][(wq + 3) * STW + wm] = np_.w;
            __syncthreads();
        }
        p ^= 1;
    }

    const int gn = n0 + tx * 4;
    const float4 tb4 = *(const float4*)(thb + gn);
    const float4 pb4 = *(const float4*)(phb + gn);
#pragma unroll
    for (int i2 = 0; i2 < 8; ++i2) {
        const int gm = row0 + ty * 8 + i2;
        const size_t off = (size_t)gm * C + gn;
        float4 xr = *(const float4*)(x + off);
        float4 tvv = make_float4(aT[i2][0], aT[i2][1], aT[i2][2], aT[i2][3]);
        float4 rv;
        rv.x = xr.x + aQ[i2][0] + tb4.x + pb4.x - tvv.x;
        rv.y = xr.y + aQ[i2][1] + tb4.y + pb4.y - tvv.y;
        rv.z = xr.z + aQ[i2][2] + tb4.z + pb4.z - tvv.z;
        rv.w = xr.w + aQ[i2][3] + tb4.w + pb4.w - tvv.w;
        *(float4*)(T + off) = tvv;
        *(float4*)(R + off) = rv;
    }
}

// ---------------------------------------------------------------------------
// K2a REWRITE: x1[i,c] = max_{k<16} T[src[i,k], c] + R[i,c], tiled by
// (batch, 4-channel slab). The whole batch's T-slab (2048x4) sits in LDS, so
// the 16-way random gather hits LDS instead of L2/L3 (268 MB -> ~48 MB HBM).
// grid (C/4=64, B=8), block 256.
// ---------------------------------------------------------------------------
__global__ __launch_bounds__(256) void k2a_gather_max(
    const int* __restrict__ esrc, const float* __restrict__ T, float* x1r)
{
    constexpr int CH = 4, TST = 5, DTILE = 64;
    __shared__ float Ts[N_PER * TST];       // 40 KB
    __shared__ int   sidx[DTILE * 17];      // 4.25 KB, stride 17 vs bank conflicts
    const int b  = blockIdx.y;
    const int c0 = blockIdx.x * CH;
    const int t  = threadIdx.x;

    // stage T slab: 2048 rows x 4 channels
    {
        const int ch = t & 3;
        for (int r = t >> 2; r < N_PER; r += 64)
            Ts[r * TST + ch] = T[((size_t)(b * N_PER + r)) * C + c0 + ch];
    }
    __syncthreads();

    const int chv = t & 3;
    const int dl  = t >> 2;                 // 0..63: dst within tile
    for (int d0 = 0; d0 < N_PER; d0 += DTILE) {
        // stage 64 dsts' edge lists (1024 ints, coalesced int4)
        const int4 e4 = *(const int4*)&esrc[((size_t)(b * N_PER + d0)) * KG + t * 4];
        const int dd = t >> 2, kk = (t & 3) * 4;
        sidx[dd * 17 + kk + 0] = e4.x;  sidx[dd * 17 + kk + 1] = e4.y;
        sidx[dd * 17 + kk + 2] = e4.z;  sidx[dd * 17 + kk + 3] = e4.w;
        __syncthreads();

        float m = -INFINITY;
#pragma unroll
        for (int k = 0; k < KG; ++k) {
            const int s = sidx[dl * 17 + k] - b * N_PER;   // local src row
            m = fmaxf(m, Ts[s * TST + chv]);
        }
        const size_t off = ((size_t)(b * N_PER + d0 + dl)) * C + c0 + chv;
        x1r[off] = m + x1r[off];
        __syncthreads();   // protect sidx before next tile overwrites it
    }
}

// ---------------------------------------------------------------------------
// K2bc: fused score MLP. Per block: 64 nodes.
// ---------------------------------------------------------------------------
__global__ __launch_bounds__(256) void k2bc_score(
    const float* __restrict__ x1, const float* __restrict__ w1,
    const float* __restrict__ b1, const float* __restrict__ g1,
    const float* __restrict__ be1, const float* __restrict__ m1,
    const float* __restrict__ v1,
    const float* __restrict__ w2, const float* __restrict__ b2,
    const float* __restrict__ g2, const float* __restrict__ be2,
    const float* __restrict__ m2, const float* __restrict__ v2,
    const float* __restrict__ w3, const float* __restrict__ b3,
    float* __restrict__ score_ws, float* __restrict__ out_score)
{
    constexpr int BK = 16, ST = 68;
    __shared__ float Xs[BK * ST];
    __shared__ float Ws[BK * ST];
    __shared__ float t1s[64 * 65];
    __shared__ float w2s[32 * 65];
    __shared__ float w3s[32];
    __shared__ float zs[64 * 33];
    const int tid  = threadIdx.x;
    const int row0 = blockIdx.x * 64;
    const int tx = tid & 15, ty = tid >> 4;
    const int lm = tid >> 2, lq = (tid & 3) << 2;

    float acc[4][4] = {{0.f}};
    for (int k0 = 0; k0 < C; k0 += BK) {
        float4 fx = *(const float4*)(x1 + (size_t)(row0 + lm) * C + k0 + lq);
        float4 fw = *(const float4*)(w1 + (size_t)lm * C + k0 + lq);
        __syncthreads();
        Xs[(lq + 0) * ST + lm] = fx.x;  Xs[(lq + 1) * ST + lm] = fx.y;
        Xs[(lq + 2) * ST + lm] = fx.z;  Xs[(lq + 3) * ST + lm] = fx.w;
        Ws[(lq + 0) * ST + lm] = fw.x;  Ws[(lq + 1) * ST + lm] = fw.y;
        Ws[(lq + 2) * ST + lm] = fw.z;  Ws[(lq + 3) * ST + lm] = fw.w;
        __syncthreads();
#pragma unroll
        for (int k = 0; k < BK; ++k) {
            float4 a4 = *(const float4*)&Xs[k * ST + (ty << 2)];
            float4 w4 = *(const float4*)&Ws[k * ST + (tx << 2)];
            float av[4] = {a4.x, a4.y, a4.z, a4.w};
            float wv[4] = {w4.x, w4.y, w4.z, w4.w};
#pragma unroll
            for (int i2 = 0; i2 < 4; ++i2)
#pragma unroll
                for (int j2 = 0; j2 < 4; ++j2) acc[i2][j2] += av[i2] * wv[j2];
        }
    }
    __syncthreads();
#pragma unroll
    for (int i2 = 0; i2 < 4; ++i2) {
        const int mrow = (ty << 2) + i2;
#pragma unroll
        for (int j2 = 0; j2 < 4; ++j2) {
            const int o = (tx << 2) + j2;
            float y = acc[i2][j2] + b1[o];
            y = fmaxf(y, 0.f);
            y = (y - m1[o]) * (1.0f / sqrtf(v1[o] + EPS)) * g1[o] + be1[o];
            t1s[mrow * 65 + o] = y;
        }
    }
    for (int idx = tid; idx < 2048; idx += 256)
        w2s[(idx >> 6) * 65 + (idx & 63)] = w2[idx];
    if (tid < 32) w3s[tid] = w3[tid];
    __syncthreads();

    const int o = tid & 31;
    const float inv2 = (1.0f / sqrtf(v2[o] + EPS)) * g2[o];
#pragma unroll
    for (int p = 0; p < 8; ++p) {
        const int nl = p * 8 + (tid >> 5);
        float z = 0.f;
#pragma unroll
        for (int j = 0; j < 64; ++j) z += t1s[nl * 65 + j] * w2s[o * 65 + j];
        z += b2[o];
        z = fmaxf(z, 0.f);
        z = (z - m2[o]) * inv2 + be2[o];
        zs[nl * 33 + o] = z;
    }
    __syncthreads();

    if (tid < 64) {
        float sacc = 0.f;
#pragma unroll
        for (int j = 0; j < 32; ++j) sacc += zs[tid * 33 + j] * w3s[j];
        sacc += b3[0];
        const int node = row0 + tid;
        score_ws[node]  = sacc;
        out_score[node] = sacc;
    }
}

// ---------------------------------------------------------------------------
// K3: per-batch top-512 of 2048, descending, ties -> lower index first.
// ---------------------------------------------------------------------------
__global__ __launch_bounds__(1024) void k3_topk(
    const float* __restrict__ score, float* __restrict__ out_topk,
    int* __restrict__ perm)
{
    __shared__ unsigned long long keys[N_PER];
    const int b = blockIdx.x;
    const int t = threadIdx.x;
    for (int i = t; i < N_PER; i += 1024) {
        const float v = score[b * N_PER + i];
        unsigned u = __float_as_uint(v);
        const unsigned ua = (u & 0x80000000u) ? ~u : (u | 0x80000000u);
        const unsigned ud = ~ua;   // descending-monotone
        keys[i] = ((unsigned long long)ud << 32) | (unsigned)i;
    }
    __syncthreads();
    for (int k = 2; k <= N_PER; k <<= 1) {
        for (int j = k >> 1; j > 0; j >>= 1) {
            for (int i = t; i < N_PER; i += 1024) {
                const int ixj = i ^ j;
                if (ixj > i) {
                    const unsigned long long a = keys[i], c = keys[ixj];
                    const bool up = ((i & k) == 0);
                    if ((a > c) == up) { keys[i] = c; keys[ixj] = a; }
                }
            }
            __syncthreads();
        }
    }
    for (int r = t; r < KTOP; r += 1024) {
        const int idx = (int)(keys[r] & 0xffffffffu);
        out_topk[b * KTOP + r] = score[b * N_PER + idx];
        perm[b * KTOP + r] = b * N_PER + idx;
    }
}

// ---------------------------------------------------------------------------
// K5: fused gather (x_new/x_copy) + 32-NN among 512 selected points.
// ---------------------------------------------------------------------------
__global__ __launch_bounds__(256) void k5_knn(
    const int* __restrict__ perm, const float* __restrict__ xyz,
    const float* __restrict__ x1, const float* __restrict__ xorig,
    float* __restrict__ out_xnew, float* __restrict__ out_xcopy,
    float* __restrict__ out_knn)
{
    constexpr int G = 4;
    __shared__ float px[KTOP], py[KTOP], pz[KTOP];
    __shared__ unsigned long long keys[G * KTOP];
    const int t  = threadIdx.x;
    const int q0 = blockIdx.x * G;
    const int b  = q0 >> 9;
    const int i0 = q0 & 511;

    for (int idx = t; idx < KTOP; idx += 256) {
        const int g = perm[b * KTOP + idx];
        px[idx] = xyz[g * 3 + 0];
        py[idx] = xyz[g * 3 + 1];
        pz[idx] = xyz[g * 3 + 2];
    }
#pragma unroll
    for (int p = 0; p < G; ++p) {
        const int row = q0 + p;
        const int g = perm[row];
        out_xnew [(size_t)row * C + t] = x1   [(size_t)g * C + t];
        out_xcopy[(size_t)row * C + t] = xorig[(size_t)g * C + t];
    }
    __syncthreads();

    for (int w = t; w < G * KTOP; w += 256) {
        const int p = w >> 9, idx = w & 511;
        const float dx = __fsub_rn(px[i0 + p], px[idx]);
        const float dy = __fsub_rn(py[i0 + p], py[idx]);
        const float dz = __fsub_rn(pz[i0 + p], pz[idx]);
        const float d2 = __fadd_rn(__fadd_rn(__fmul_rn(dx, dx), __fmul_rn(dy, dy)),
                                   __fmul_rn(dz, dz));
        keys[w] = ((unsigned long long)__float_as_uint(d2) << 32) | (unsigned)idx;
    }
    __syncthreads();

    for (int k = 2; k <= 32; k <<= 1) {
        for (int j = k >> 1; j > 0; j >>= 1) {
            for (int i = t; i < G * KTOP; i += 256) {
                const int ixj = i ^ j;
                if (ixj > i) {
                    const int il = i & 31;
                    const unsigned long long a = keys[i], c = keys[ixj];
                    const bool up = ((il & k) == 0) || (k == 32);
                    if ((a > c) == up) { keys[i] = c; keys[ixj] = a; }
                }
            }
            __syncthreads();
        }
    }
    for (int r = 0; r < 4; ++r) {
        const int npairs = 8 >> r;
        const int total  = G * npairs * 32;
        for (int w = t; w < total; w += 256) {
            const int p  = w / (npairs * 32);
            const int rm = w - p * (npairs * 32);
            const int m  = rm >> 5, i = rm & 31;
            const int baseA = p * KTOP + m * (64 << r);
            const int baseB = baseA + (32 << r);
            const unsigned long long a = keys[baseA + i];
            const unsigned long long c = keys[baseB + 31 - i];
            keys[baseA + i] = (c < a) ? c : a;
        }
        __syncthreads();
        for (int j = 16; j > 0; j >>= 1) {
            for (int w = t; w < total; w += 256) {
                const int p  = w / (npairs * 32);
                const int rm = w - p * (npairs * 32);
                const int m  = rm >> 5, i = rm & 31;
                const int ixj = i ^ j;
                if (ixj > i) {
                    const int baseA = p * KTOP + m * (64 << r);
                    const unsigned long long a = keys[baseA + i], c = keys[baseA + ixj];
                    if (a > c) { keys[baseA + i] = c; keys[baseA + ixj] = a; }
                }
            }
            __syncthreads();
        }
    }

    if (t < G * KNN) {
        const int p = t >> 5, r = t & 31;
        out_knn[((size_t)(q0 + p)) * KNN + r] =
            (float)(unsigned)(keys[p * KTOP + r] & 0xffffffffu);
    }
}

// ---------------------------------------------------------------------------
extern "C" void kernel_launch(void* const* d_in, const int* in_sizes, int n_in,
                              void* d_out, int out_size, void* d_ws, size_t ws_size,
                              hipStream_t stream)
{
    const float* x     = (const float*)d_in[0];
    const float* xorig = (const float*)d_in[1];
    const float* xyz   = (const float*)d_in[2];
    const int*   esrc  = (const int*)d_in[3];
    const float* thw = (const float*)d_in[5];
    const float* thb = (const float*)d_in[6];
    const float* phw = (const float*)d_in[7];
    const float* phb = (const float*)d_in[8];
    const float* w1  = (const float*)d_in[9];
    const float* b1  = (const float*)d_in[10];
    const float* g1  = (const float*)d_in[11];
    const float* be1 = (const float*)d_in[12];
    const float* m1  = (const float*)d_in[13];
    const float* v1  = (const float*)d_in[14];
    const float* w2  = (const float*)d_in[15];
    const float* b2  = (const float*)d_in[16];
    const float* g2  = (const float*)d_in[17];
    const float* be2 = (const float*)d_in[18];
    const float* m2  = (const float*)d_in[19];
    const float* v2  = (const float*)d_in[20];
    const float* w3  = (const float*)d_in[21];
    const float* b3  = (const float*)d_in[22];

    float* ws   = (float*)d_ws;
    float* T    = ws;                          // N*C
    float* x1   = ws + (size_t)N * C;          // N*C  (R from k1, becomes x1)
    float* sc   = ws + 2 * (size_t)N * C;      // N
    int*   perm = (int*)(sc + N);              // B*KTOP

    float* out     = (float*)d_out;
    float* o_knn   = out;                                  // B*KTOP*KNN
    float* o_xnew  = o_knn + (size_t)B * KTOP * KNN;       // B*KTOP*C
    float* o_xcopy = o_xnew + (size_t)B * KTOP * C;        // B*KTOP*C
    float* o_score = o_xcopy + (size_t)B * KTOP * C;       // B*N_PER
    float* o_topk  = o_score + (size_t)B * N_PER;          // B*KTOP

    k1_dual_gemm<<<dim3(N / 128, C / 64), 256, 0, stream>>>(x, thw, phw, thb, phb, T, x1);
    k2a_gather_max<<<dim3(C / 4, B), 256, 0, stream>>>(esrc, T, x1);
    k2bc_score<<<N / 64, 256, 0, stream>>>(x1, w1, b1, g1, be1, m1, v1,
                                           w2, b2, g2, be2, m2, v2, w3, b3, sc, o_score);
    k3_topk<<<B, 1024, 0, stream>>>(sc, o_topk, perm);
    k5_knn<<<B * KTOP / 4, 256, 0, stream>>>(perm, xyz, x1, xorig,
                                             o_xnew, o_xcopy, o_knn);
}

// Round 5
// 266.496 us; speedup vs baseline: 1.1909x; 1.1909x over previous
//
#include <hip/hip_runtime.h>
#include <math.h>

// Problem constants (fixed by the reference)
constexpr int B     = 8;
constexpr int N_PER = 2048;
constexpr int C     = 256;
constexpr int KG    = 16;
constexpr int KTOP  = 512;
constexpr int KNN   = 32;
constexpr int N     = B * N_PER;   // 16384
constexpr float EPS = 1e-5f;

// ---------------------------------------------------------------------------
// K1: T = x @ theta_w.T ;  R = x + x @ phi_w.T + (theta_b + phi_b) - T
// 128x64 tile, 8x4 dual accumulators, double-buffered LDS (1 barrier/tile).
// grid (N/128, C/64) = 512 blocks, block 256.
// ---------------------------------------------------------------------------
__global__ __launch_bounds__(256, 2) void k1_dual_gemm(
    const float* __restrict__ x, const float* __restrict__ thw,
    const float* __restrict__ phw, const float* __restrict__ thb,
    const float* __restrict__ phb, float* __restrict__ T, float* __restrict__ R)
{
    constexpr int BK = 16, STX = 132, STW = 68;
    __shared__ float Xs[2][BK * STX];
    __shared__ float Wt[2][BK * STW];
    __shared__ float Wp[2][BK * STW];
    const int tid  = threadIdx.x;
    const int row0 = blockIdx.x * 128;
    const int n0   = blockIdx.y * 64;
    const int tx = tid & 15, ty = tid >> 4;
    const int lm = tid >> 1, lq = (tid & 1) * 8;
    const int wm = tid >> 2, wq = (tid & 3) * 4;

    float aT[8][4] = {{0.f}}, aQ[8][4] = {{0.f}};

    float4 nx0 = *(const float4*)(x   + (size_t)(row0 + lm) * C + lq);
    float4 nx1 = *(const float4*)(x   + (size_t)(row0 + lm) * C + lq + 4);
    float4 nt  = *(const float4*)(thw + (size_t)(n0   + wm) * C + wq);
    float4 np_ = *(const float4*)(phw + (size_t)(n0   + wm) * C + wq);
    Xs[0][(lq + 0) * STX + lm] = nx0.x;  Xs[0][(lq + 1) * STX + lm] = nx0.y;
    Xs[0][(lq + 2) * STX + lm] = nx0.z;  Xs[0][(lq + 3) * STX + lm] = nx0.w;
    Xs[0][(lq + 4) * STX + lm] = nx1.x;  Xs[0][(lq + 5) * STX + lm] = nx1.y;
    Xs[0][(lq + 6) * STX + lm] = nx1.z;  Xs[0][(lq + 7) * STX + lm] = nx1.w;
    Wt[0][(wq + 0) * STW + wm] = nt.x;   Wt[0][(wq + 1) * STW + wm] = nt.y;
    Wt[0][(wq + 2) * STW + wm] = nt.z;   Wt[0][(wq + 3) * STW + wm] = nt.w;
    Wp[0][(wq + 0) * STW + wm] = np_.x;  Wp[0][(wq + 1) * STW + wm] = np_.y;
    Wp[0][(wq + 2) * STW + wm] = np_.z;  Wp[0][(wq + 3) * STW + wm] = np_.w;
    __syncthreads();

    int p = 0;
    for (int k0 = 0; k0 < C; k0 += BK) {
        const int kn = k0 + BK;
        if (kn < C) {
            nx0 = *(const float4*)(x   + (size_t)(row0 + lm) * C + kn + lq);
            nx1 = *(const float4*)(x   + (size_t)(row0 + lm) * C + kn + lq + 4);
            nt  = *(const float4*)(thw + (size_t)(n0   + wm) * C + kn + wq);
            np_ = *(const float4*)(phw + (size_t)(n0   + wm) * C + kn + wq);
        }
        const float* Xp = Xs[p];
        const float* Tp = Wt[p];
        const float* Pp = Wp[p];
#pragma unroll
        for (int k = 0; k < BK; ++k) {
            float4 alo = *(const float4*)&Xp[k * STX + ty * 8];
            float4 ahi = *(const float4*)&Xp[k * STX + ty * 8 + 4];
            float4 tv4 = *(const float4*)&Tp[k * STW + tx * 4];
            float4 pv4 = *(const float4*)&Pp[k * STW + tx * 4];
            float av[8] = {alo.x, alo.y, alo.z, alo.w, ahi.x, ahi.y, ahi.z, ahi.w};
            float tv[4] = {tv4.x, tv4.y, tv4.z, tv4.w};
            float pv[4] = {pv4.x, pv4.y, pv4.z, pv4.w};
#pragma unroll
            for (int i2 = 0; i2 < 8; ++i2)
#pragma unroll
                for (int j2 = 0; j2 < 4; ++j2) {
                    aT[i2][j2] += av[i2] * tv[j2];
                    aQ[i2][j2] += av[i2] * pv[j2];
                }
        }
        if (kn < C) {
            const int q = p ^ 1;
            Xs[q][(lq + 0) * STX + lm] = nx0.x;  Xs[q][(lq + 1) * STX + lm] = nx0.y;
            Xs[q][(lq + 2) * STX + lm] = nx0.z;  Xs[q][(lq + 3) * STX + lm] = nx0.w;
            Xs[q][(lq + 4) * STX + lm] = nx1.x;  Xs[q][(lq + 5) * STX + lm] = nx1.y;
            Xs[q][(lq + 6) * STX + lm] = nx1.z;  Xs[q][(lq + 7) * STX + lm] = nx1.w;
            Wt[q][(wq + 0) * STW + wm] = nt.x;   Wt[q][(wq + 1) * STW + wm] = nt.y;
            Wt[q][(wq + 2) * STW + wm] = nt.z;   Wt[q][(wq + 3) * STW + wm] = nt.w;
            Wp[q][(wq + 0) * STW + wm] = np_.x;  Wp[q][(wq + 1) * STW + wm] = np_.y;
            Wp[q][(wq + 2) * STW + wm] = np_.z;  Wp[q][(wq + 3) * STW + wm] = np_.w;
            __syncthreads();
        }
        p ^= 1;
    }

    const int gn = n0 + tx * 4;
    const float4 tb4 = *(const float4*)(thb + gn);
    const float4 pb4 = *(const float4*)(phb + gn);
#pragma unroll
    for (int i2 = 0; i2 < 8; ++i2) {
        const int gm = row0 + ty * 8 + i2;
        const size_t off = (size_t)gm * C + gn;
        float4 xr = *(const float4*)(x + off);
        float4 tvv = make_float4(aT[i2][0], aT[i2][1], aT[i2][2], aT[i2][3]);
        float4 rv;
        rv.x = xr.x + aQ[i2][0] + tb4.x + pb4.x - tvv.x;
        rv.y = xr.y + aQ[i2][1] + tb4.y + pb4.y - tvv.y;
        rv.z = xr.z + aQ[i2][2] + tb4.z + pb4.z - tvv.z;
        rv.w = xr.w + aQ[i2][3] + tb4.w + pb4.w - tvv.w;
        *(float4*)(T + off) = tvv;
        *(float4*)(R + off) = rv;
    }
}

// ---------------------------------------------------------------------------
// K2a (reverted to R3 form + XCD swizzle): x1[i] = max_k T[src[i,k]] + R[i].
// batch = blockIdx & 7: with round-robin block->XCD dispatch each XCD's 4MB L2
// caches exactly its batch's 2MB T-slab, so the 16-way gather re-reads hit L2.
// grid N/4 = 4096, block 256 (4 nodes/block, one node per wave, float4 lanes).
// ---------------------------------------------------------------------------
__global__ __launch_bounds__(256) void k2a_gather_max(
    const int* __restrict__ esrc, const float* __restrict__ T, float* x1r)
{
    const int gb = blockIdx.x;
    const int b  = gb & 7;                    // batch -> XCD (L2 locality)
    const int node0 = b * N_PER + (gb >> 3) * 4;
    const int t = threadIdx.x;
    __shared__ int s[4][KG];
    if (t < 64) s[t >> 4][t & 15] = esrc[(node0 + (t >> 4)) * KG + (t & 15)];
    __syncthreads();
    const int m  = t >> 6;
    const int c4 = (t & 63) * 4;
    float4 acc = make_float4(-INFINITY, -INFINITY, -INFINITY, -INFINITY);
#pragma unroll
    for (int k = 0; k < KG; ++k) {
        const float4 v = *(const float4*)&T[(size_t)s[m][k] * C + c4];
        acc.x = fmaxf(acc.x, v.x);  acc.y = fmaxf(acc.y, v.y);
        acc.z = fmaxf(acc.z, v.z);  acc.w = fmaxf(acc.w, v.w);
    }
    const size_t off = (size_t)(node0 + m) * C + c4;
    float4 r = *(const float4*)&x1r[off];
    r.x += acc.x;  r.y += acc.y;  r.z += acc.z;  r.w += acc.w;
    *(float4*)&x1r[off] = r;
}

// ---------------------------------------------------------------------------
// K2bc: fused score MLP. Per block: 64 nodes.
// ---------------------------------------------------------------------------
__global__ __launch_bounds__(256) void k2bc_score(
    const float* __restrict__ x1, const float* __restrict__ w1,
    const float* __restrict__ b1, const float* __restrict__ g1,
    const float* __restrict__ be1, const float* __restrict__ m1,
    const float* __restrict__ v1,
    const float* __restrict__ w2, const float* __restrict__ b2,
    const float* __restrict__ g2, const float* __restrict__ be2,
    const float* __restrict__ m2, const float* __restrict__ v2,
    const float* __restrict__ w3, const float* __restrict__ b3,
    float* __restrict__ score_ws, float* __restrict__ out_score)
{
    constexpr int BK = 16, ST = 68;
    __shared__ float Xs[BK * ST];
    __shared__ float Ws[BK * ST];
    __shared__ float t1s[64 * 65];
    __shared__ float w2s[32 * 65];
    __shared__ float w3s[32];
    __shared__ float zs[64 * 33];
    const int tid  = threadIdx.x;
    const int row0 = blockIdx.x * 64;
    const int tx = tid & 15, ty = tid >> 4;
    const int lm = tid >> 2, lq = (tid & 3) << 2;

    float acc[4][4] = {{0.f}};
    for (int k0 = 0; k0 < C; k0 += BK) {
        float4 fx = *(const float4*)(x1 + (size_t)(row0 + lm) * C + k0 + lq);
        float4 fw = *(const float4*)(w1 + (size_t)lm * C + k0 + lq);
        __syncthreads();
        Xs[(lq + 0) * ST + lm] = fx.x;  Xs[(lq + 1) * ST + lm] = fx.y;
        Xs[(lq + 2) * ST + lm] = fx.z;  Xs[(lq + 3) * ST + lm] = fx.w;
        Ws[(lq + 0) * ST + lm] = fw.x;  Ws[(lq + 1) * ST + lm] = fw.y;
        Ws[(lq + 2) * ST + lm] = fw.z;  Ws[(lq + 3) * ST + lm] = fw.w;
        __syncthreads();
#pragma unroll
        for (int k = 0; k < BK; ++k) {
            float4 a4 = *(const float4*)&Xs[k * ST + (ty << 2)];
            float4 w4 = *(const float4*)&Ws[k * ST + (tx << 2)];
            float av[4] = {a4.x, a4.y, a4.z, a4.w};
            float wv[4] = {w4.x, w4.y, w4.z, w4.w};
#pragma unroll
            for (int i2 = 0; i2 < 4; ++i2)
#pragma unroll
                for (int j2 = 0; j2 < 4; ++j2) acc[i2][j2] += av[i2] * wv[j2];
        }
    }
    __syncthreads();
#pragma unroll
    for (int i2 = 0; i2 < 4; ++i2) {
        const int mrow = (ty << 2) + i2;
#pragma unroll
        for (int j2 = 0; j2 < 4; ++j2) {
            const int o = (tx << 2) + j2;
            float y = acc[i2][j2] + b1[o];
            y = fmaxf(y, 0.f);
            y = (y - m1[o]) * (1.0f / sqrtf(v1[o] + EPS)) * g1[o] + be1[o];
            t1s[mrow * 65 + o] = y;
        }
    }
    for (int idx = tid; idx < 2048; idx += 256)
        w2s[(idx >> 6) * 65 + (idx & 63)] = w2[idx];
    if (tid < 32) w3s[tid] = w3[tid];
    __syncthreads();

    const int o = tid & 31;
    const float inv2 = (1.0f / sqrtf(v2[o] + EPS)) * g2[o];
#pragma unroll
    for (int p = 0; p < 8; ++p) {
        const int nl = p * 8 + (tid >> 5);
        float z = 0.f;
#pragma unroll
        for (int j = 0; j < 64; ++j) z += t1s[nl * 65 + j] * w2s[o * 65 + j];
        z += b2[o];
        z = fmaxf(z, 0.f);
        z = (z - m2[o]) * inv2 + be2[o];
        zs[nl * 33 + o] = z;
    }
    __syncthreads();

    if (tid < 64) {
        float sacc = 0.f;
#pragma unroll
        for (int j = 0; j < 32; ++j) sacc += zs[tid * 33 + j] * w3s[j];
        sacc += b3[0];
        const int node = row0 + tid;
        score_ws[node]  = sacc;
        out_score[node] = sacc;
    }
}

// ---------------------------------------------------------------------------
// K3: per-batch top-512 of 2048, descending, ties -> lower index first.
// Epilogue also writes xsel (selected xyz) so k5 can stage coalesced.
// ---------------------------------------------------------------------------
__global__ __launch_bounds__(1024) void k3_topk(
    const float* __restrict__ score, const float* __restrict__ xyz,
    float* __restrict__ out_topk, int* __restrict__ perm,
    float* __restrict__ xsel)
{
    __shared__ unsigned long long keys[N_PER];
    const int b = blockIdx.x;
    const int t = threadIdx.x;
    for (int i = t; i < N_PER; i += 1024) {
        const float v = score[b * N_PER + i];
        unsigned u = __float_as_uint(v);
        const unsigned ua = (u & 0x80000000u) ? ~u : (u | 0x80000000u);
        const unsigned ud = ~ua;   // descending-monotone
        keys[i] = ((unsigned long long)ud << 32) | (unsigned)i;
    }
    __syncthreads();
    for (int k = 2; k <= N_PER; k <<= 1) {
        for (int j = k >> 1; j > 0; j >>= 1) {
            for (int i = t; i < N_PER; i += 1024) {
                const int ixj = i ^ j;
                if (ixj > i) {
                    const unsigned long long a = keys[i], c = keys[ixj];
                    const bool up = ((i & k) == 0);
                    if ((a > c) == up) { keys[i] = c; keys[ixj] = a; }
                }
            }
            __syncthreads();
        }
    }
    for (int r = t; r < KTOP; r += 1024) {
        const int idx = (int)(keys[r] & 0xffffffffu);
        const int g = b * N_PER + idx;
        out_topk[b * KTOP + r] = score[g];
        perm[b * KTOP + r] = g;
        xsel[(b * KTOP + r) * 3 + 0] = xyz[g * 3 + 0];
        xsel[(b * KTOP + r) * 3 + 1] = xyz[g * 3 + 1];
        xsel[(b * KTOP + r) * 3 + 2] = xyz[g * 3 + 2];
    }
}

// ---------------------------------------------------------------------------
// K5: fused gather (x_new/x_copy) + 32-NN among 512 selected points.
// xyz staged coalesced from xsel (contiguous 6KB per batch).
// grid B*KTOP/4 = 1024, block 256.
// ---------------------------------------------------------------------------
__global__ __launch_bounds__(256) void k5_knn(
    const int* __restrict__ perm, const float* __restrict__ xsel,
    const float* __restrict__ x1, const float* __restrict__ xorig,
    float* __restrict__ out_xnew, float* __restrict__ out_xcopy,
    float* __restrict__ out_knn)
{
    constexpr int G = 4;
    __shared__ float px[KTOP], py[KTOP], pz[KTOP];
    __shared__ unsigned long long keys[G * KTOP];
    const int t  = threadIdx.x;
    const int q0 = blockIdx.x * G;
    const int b  = q0 >> 9;
    const int i0 = q0 & 511;

    for (int idx = t; idx < KTOP; idx += 256) {
        const size_t base = ((size_t)b * KTOP + idx) * 3;
        px[idx] = xsel[base + 0];
        py[idx] = xsel[base + 1];
        pz[idx] = xsel[base + 2];
    }
#pragma unroll
    for (int p = 0; p < G; ++p) {
        const int row = q0 + p;
        const int g = perm[row];
        out_xnew [(size_t)row * C + t] = x1   [(size_t)g * C + t];
        out_xcopy[(size_t)row * C + t] = xorig[(size_t)g * C + t];
    }
    __syncthreads();

    for (int w = t; w < G * KTOP; w += 256) {
        const int p = w >> 9, idx = w & 511;
        const float dx = __fsub_rn(px[i0 + p], px[idx]);
        const float dy = __fsub_rn(py[i0 + p], py[idx]);
        const float dz = __fsub_rn(pz[i0 + p], pz[idx]);
        const float d2 = __fadd_rn(__fadd_rn(__fmul_rn(dx, dx), __fmul_rn(dy, dy)),
                                   __fmul_rn(dz, dz));
        keys[w] = ((unsigned long long)__float_as_uint(d2) << 32) | (unsigned)idx;
    }
    __syncthreads();

    for (int k = 2; k <= 32; k <<= 1) {
        for (int j = k >> 1; j > 0; j >>= 1) {
            for (int i = t; i < G * KTOP; i += 256) {
                const int ixj = i ^ j;
                if (ixj > i) {
                    const int il = i & 31;
                    const unsigned long long a = keys[i], c = keys[ixj];
                    const bool up = ((il & k) == 0) || (k == 32);
                    if ((a > c) == up) { keys[i] = c; keys[ixj] = a; }
                }
            }
            __syncthreads();
        }
    }
    for (int r = 0; r < 4; ++r) {
        const int npairs = 8 >> r;
        const int total  = G * npairs * 32;
        for (int w = t; w < total; w += 256) {
            const int p  = w / (npairs * 32);
            const int rm = w - p * (npairs * 32);
            const int m  = rm >> 5, i = rm & 31;
            const int baseA = p * KTOP + m * (64 << r);
            const int baseB = baseA + (32 << r);
            const unsigned long long a = keys[baseA + i];
            const unsigned long long c = keys[baseB + 31 - i];
            keys[baseA + i] = (c < a) ? c : a;
        }
        __syncthreads();
        for (int j = 16; j > 0; j >>= 1) {
            for (int w = t; w < total; w += 256) {
                const int p  = w / (npairs * 32);
                const int rm = w - p * (npairs * 32);
                const int m  = rm >> 5, i = rm & 31;
                const int ixj = i ^ j;
                if (ixj > i) {
                    const int baseA = p * KTOP + m * (64 << r);
                    const unsigned long long a = keys[baseA + i], c = keys[baseA + ixj];
                    if (a > c) { keys[baseA + i] = c; keys[baseA + ixj] = a; }
                }
            }
            __syncthreads();
        }
    }

    if (t < G * KNN) {
        const int p = t >> 5, r = t & 31;
        out_knn[((size_t)(q0 + p)) * KNN + r] =
            (float)(unsigned)(keys[p * KTOP + r] & 0xffffffffu);
    }
}

// ---------------------------------------------------------------------------
extern "C" void kernel_launch(void* const* d_in, const int* in_sizes, int n_in,
                              void* d_out, int out_size, void* d_ws, size_t ws_size,
                              hipStream_t stream)
{
    const float* x     = (const float*)d_in[0];
    const float* xorig = (const float*)d_in[1];
    const float* xyz   = (const float*)d_in[2];
    const int*   esrc  = (const int*)d_in[3];
    const float* thw = (const float*)d_in[5];
    const float* thb = (const float*)d_in[6];
    const float* phw = (const float*)d_in[7];
    const float* phb = (const float*)d_in[8];
    const float* w1  = (const float*)d_in[9];
    const float* b1  = (const float*)d_in[10];
    const float* g1  = (const float*)d_in[11];
    const float* be1 = (const float*)d_in[12];
    const float* m1  = (const float*)d_in[13];
    const float* v1  = (const float*)d_in[14];
    const float* w2  = (const float*)d_in[15];
    const float* b2  = (const float*)d_in[16];
    const float* g2  = (const float*)d_in[17];
    const float* be2 = (const float*)d_in[18];
    const float* m2  = (const float*)d_in[19];
    const float* v2  = (const float*)d_in[20];
    const float* w3  = (const float*)d_in[21];
    const float* b3  = (const float*)d_in[22];

    float* ws   = (float*)d_ws;
    float* T    = ws;                          // N*C
    float* x1   = ws + (size_t)N * C;          // N*C  (R from k1, becomes x1)
    float* sc   = ws + 2 * (size_t)N * C;      // N
    int*   perm = (int*)(sc + N);              // B*KTOP
    float* xsel = (float*)(perm + B * KTOP);   // B*KTOP*3

    float* out     = (float*)d_out;
    float* o_knn   = out;                                  // B*KTOP*KNN
    float* o_xnew  = o_knn + (size_t)B * KTOP * KNN;       // B*KTOP*C
    float* o_xcopy = o_xnew + (size_t)B * KTOP * C;        // B*KTOP*C
    float* o_score = o_xcopy + (size_t)B * KTOP * C;       // B*N_PER
    float* o_topk  = o_score + (size_t)B * N_PER;          // B*KTOP

    k1_dual_gemm<<<dim3(N / 128, C / 64), 256, 0, stream>>>(x, thw, phw, thb, phb, T, x1);
    k2a_gather_max<<<N / 4, 256, 0, stream>>>(esrc, T, x1);
    k2bc_score<<<N / 64, 256, 0, stream>>>(x1, w1, b1, g1, be1, m1, v1,
                                           w2, b2, g2, be2, m2, v2, w3, b3, sc, o_score);
    k3_topk<<<B, 1024, 0, stream>>>(sc, xyz, o_topk, perm, xsel);
    k5_knn<<<B * KTOP / 4, 256, 0, stream>>>(perm, xsel, x1, xorig,
                                             o_xnew, o_xcopy, o_knn);
}